// Round 1
// baseline (754.347 us; speedup 1.0000x reference)
//
#include <hip/hip_runtime.h>
#include <stdint.h>

typedef short short8 __attribute__((ext_vector_type(8)));
typedef unsigned short ushort8 __attribute__((ext_vector_type(8)));
typedef float f32x4 __attribute__((ext_vector_type(4)));

#define HD 2048
#define S_LEN 2048
#define NROWS 8192
#define N3 6144

typedef __attribute__((address_space(3))) void lds_void_t;
typedef __attribute__((address_space(1))) void g_void_t;

__device__ inline void gload_lds16(const void* g, void* l) {
    __builtin_amdgcn_global_load_lds((g_void_t*)g, (lds_void_t*)l, 16, 0, 0);
}

__device__ inline unsigned short f2bf(float f) {
    unsigned u = __float_as_uint(f);
    unsigned r = (u + 0x7FFFu + ((u >> 16) & 1u)) >> 16;
    return (unsigned short)r;
}
__device__ inline float bf2f(unsigned short h) {
    return __uint_as_float(((unsigned)h) << 16);
}

// ---------------- LayerNorm fp32 -> bf16 ----------------
__global__ __launch_bounds__(256) void ln_kernel(const float* __restrict__ x,
    const float* __restrict__ gamma, const float* __restrict__ beta,
    unsigned short* __restrict__ xn) {
    int row = blockIdx.x;
    const float* xr = x + (size_t)row * HD;
    int tid = threadIdx.x;
    float v[8];
    float4 a = *(const float4*)(xr + tid * 8);
    float4 b = *(const float4*)(xr + tid * 8 + 4);
    v[0]=a.x; v[1]=a.y; v[2]=a.z; v[3]=a.w; v[4]=b.x; v[5]=b.y; v[6]=b.z; v[7]=b.w;
    float s = 0.f, ss = 0.f;
#pragma unroll
    for (int e = 0; e < 8; e++) { s += v[e]; ss += v[e] * v[e]; }
    for (int off = 32; off > 0; off >>= 1) {
        s += __shfl_down(s, off);
        ss += __shfl_down(ss, off);
    }
    __shared__ float red[10];
    int wave = tid >> 6, lane = tid & 63;
    if (lane == 0) { red[wave] = s; red[4 + wave] = ss; }
    __syncthreads();
    if (tid == 0) {
        float S = red[0] + red[1] + red[2] + red[3];
        float SS = red[4] + red[5] + red[6] + red[7];
        float mu = S * (1.0f / HD);
        float var = SS * (1.0f / HD) - mu * mu;
        red[8] = mu;
        red[9] = rsqrtf(var + 1e-5f);
    }
    __syncthreads();
    float mu = red[8], rstd = red[9];
#pragma unroll
    for (int e = 0; e < 8; e++) {
        int c = tid * 8 + e;
        float val = (v[e] - mu) * rstd * gamma[c] + beta[c];
        xn[(size_t)row * HD + c] = f2bf(val);
    }
}

// ---------------- transpose + cast fp32 -> bf16 ----------------
// src [rows x cols] fp32, dst [cols x rows] bf16. grid=(cols/32, rows/32)
__global__ __launch_bounds__(256) void transp_f32_bf16(const float* __restrict__ src, int ld_s,
    unsigned short* __restrict__ dst, int ld_d) {
    __shared__ float tile[32][33];
    int c0 = blockIdx.x * 32, r0 = blockIdx.y * 32;
    int tc = threadIdx.x & 31, tr = threadIdx.x >> 5; // tr 0..7
#pragma unroll
    for (int i = 0; i < 32; i += 8)
        tile[tr + i][tc] = src[(size_t)(r0 + tr + i) * ld_s + c0 + tc];
    __syncthreads();
#pragma unroll
    for (int i = 0; i < 32; i += 8)
        dst[(size_t)(c0 + tr + i) * ld_d + r0 + tc] = f2bf(tile[tc][tr + i]);
}

// bf16 -> bf16 transpose, batched over z
__global__ __launch_bounds__(256) void transp_bf16(const unsigned short* __restrict__ src0, int ld_s, long sSz,
    unsigned short* __restrict__ dst0, int ld_d, long sDz) {
    const unsigned short* src = src0 + (size_t)blockIdx.z * sSz;
    unsigned short* dst = dst0 + (size_t)blockIdx.z * sDz;
    __shared__ unsigned short tile[32][33];
    int c0 = blockIdx.x * 32, r0 = blockIdx.y * 32;
    int tc = threadIdx.x & 31, tr = threadIdx.x >> 5;
#pragma unroll
    for (int i = 0; i < 32; i += 8)
        tile[tr + i][tc] = src[(size_t)(r0 + tr + i) * ld_s + c0 + tc];
    __syncthreads();
#pragma unroll
    for (int i = 0; i < 32; i += 8)
        dst[(size_t)(c0 + tr + i) * ld_d + r0 + tc] = tile[tc][tr + i];
}

// ---------------- causal softmax over bf16 scores, in place ----------------
__global__ __launch_bounds__(256) void softmax_causal(unsigned short* __restrict__ sc) {
    int r = blockIdx.x;            // 0..8191 = b*2048+s
    int s = r & (S_LEN - 1);
    unsigned short* row = sc + (size_t)r * S_LEN;
    int tid = threadIdx.x;
    ushort8 u = *(const ushort8*)(row + tid * 8);
    float v[8];
    float mx = -3.0e38f;
#pragma unroll
    for (int e = 0; e < 8; e++) {
        int t = tid * 8 + e;
        float f = bf2f(u[e]);
        v[e] = (t <= s) ? f : -3.0e38f;
        mx = fmaxf(mx, v[e]);
    }
    for (int off = 32; off > 0; off >>= 1) mx = fmaxf(mx, __shfl_down(mx, off));
    __shared__ float red[8];
    int wave = tid >> 6, lane = tid & 63;
    if (lane == 0) red[wave] = mx;
    __syncthreads();
    mx = fmaxf(fmaxf(red[0], red[1]), fmaxf(red[2], red[3]));
    float ex[8];
    float sum = 0.f;
#pragma unroll
    for (int e = 0; e < 8; e++) {
        ex[e] = (v[e] > -1.0e38f) ? __expf(v[e] - mx) : 0.f;
        sum += ex[e];
    }
    for (int off = 32; off > 0; off >>= 1) sum += __shfl_down(sum, off);
    if (lane == 0) red[4 + wave] = sum;
    __syncthreads();
    float inv = 1.0f / (red[4] + red[5] + red[6] + red[7]);
#pragma unroll
    for (int e = 0; e < 8; e++) {
        row[tid * 8 + e] = f2bf(ex[e] * inv);
    }
}

// ---------------- NT GEMM: C[m,n] = sum_k A[m,k] * Bt[n,k] ----------------
// 128x128 tile, BK=32, 4 waves (2x2), each wave 64x64 = 4x4 of 16x16x32 MFMA.
// EPI 0: bf16 store. EPI 1: bf16 store * scale. EPI 2: fp32 store + residual.
// causal 0: none. 1: skip blocks with bx>by (scores). 2: clip K at (by+1)*128 (PV).
template <int EPI>
__global__ __launch_bounds__(256) void gemm_nt(
    const unsigned short* __restrict__ Ab, int lda, long sAz,
    const unsigned short* __restrict__ Bb, int ldb, long sBz,
    void* __restrict__ Cb, int ldc, long sCz,
    int kdim, int causal, float scale, const float* __restrict__ resid) {
    int bx = blockIdx.x, by = blockIdx.y, bz = blockIdx.z;
    if (causal == 1 && bx > by) return;
    const unsigned short* A = Ab + (size_t)bz * sAz;
    const unsigned short* Bt = Bb + (size_t)bz * sBz;
    int kmax = kdim;
    if (causal == 2) { int km = (by + 1) * 128; if (km < kmax) kmax = km; }
    int m0 = by * 128, n0 = bx * 128;

    __shared__ unsigned short lA[128 * 32];
    __shared__ unsigned short lB[128 * 32];

    int tid = threadIdx.x;
    int wave = tid >> 6, lane = tid & 63;
    int quad = lane >> 4, l16 = lane & 15;
    int wr = wave >> 1, wc = wave & 1;

    // staging map: wave w issues 2 chunks/tile; rows wave*32 + lane/4 (+16)
    int rs = wave * 32 + (lane >> 2);
    int ck = (lane & 3) * 8;
    const unsigned short* gA0 = A + (size_t)(m0 + rs) * lda + ck;
    const unsigned short* gA1 = gA0 + (size_t)16 * lda;
    const unsigned short* gB0 = Bt + (size_t)(n0 + rs) * ldb + ck;
    const unsigned short* gB1 = gB0 + (size_t)16 * ldb;
    unsigned short* lA0 = &lA[(wave * 2 + 0) * 512];
    unsigned short* lA1 = &lA[(wave * 2 + 1) * 512];
    unsigned short* lB0 = &lB[(wave * 2 + 0) * 512];
    unsigned short* lB1 = &lB[(wave * 2 + 1) * 512];

    f32x4 acc[4][4] = {};

    for (int k0 = 0; k0 < kmax; k0 += 32) {
        __syncthreads();
        gload_lds16(gA0 + k0, lA0);
        gload_lds16(gA1 + k0, lA1);
        gload_lds16(gB0 + k0, lB0);
        gload_lds16(gB1 + k0, lB1);
        __syncthreads();
        short8 af[4], bfr[4];
#pragma unroll
        for (int i = 0; i < 4; i++)
            af[i] = *(const short8*)&lA[(wr * 64 + i * 16 + l16) * 32 + quad * 8];
#pragma unroll
        for (int j = 0; j < 4; j++)
            bfr[j] = *(const short8*)&lB[(wc * 64 + j * 16 + l16) * 32 + quad * 8];
#pragma unroll
        for (int i = 0; i < 4; i++)
#pragma unroll
            for (int j = 0; j < 4; j++)
                acc[i][j] = __builtin_amdgcn_mfma_f32_16x16x32_bf16(af[i], bfr[j], acc[i][j], 0, 0, 0);
    }

    // epilogue: C[row = m0+wr*64+i*16+quad*4+r][col = n0+wc*64+j*16+l16]
    int row0 = m0 + wr * 64 + quad * 4;
    int col0 = n0 + wc * 64 + l16;
    if (EPI == 0 || EPI == 1) {
        unsigned short* C = (unsigned short*)Cb + (size_t)bz * sCz;
#pragma unroll
        for (int i = 0; i < 4; i++)
#pragma unroll
            for (int r = 0; r < 4; r++) {
                int row = row0 + i * 16 + r;
#pragma unroll
                for (int j = 0; j < 4; j++) {
                    float v = acc[i][j][r];
                    if (EPI == 1) v *= scale;
                    C[(size_t)row * ldc + col0 + j * 16] = f2bf(v);
                }
            }
    } else {
        float* C = (float*)Cb + (size_t)bz * sCz;
#pragma unroll
        for (int i = 0; i < 4; i++)
#pragma unroll
            for (int r = 0; r < 4; r++) {
                int row = row0 + i * 16 + r;
#pragma unroll
                for (int j = 0; j < 4; j++) {
                    int col = col0 + j * 16;
                    C[(size_t)row * ldc + col] = acc[i][j][r] + resid[(size_t)row * ldc + col];
                }
            }
    }
}

extern "C" void kernel_launch(void* const* d_in, const int* in_sizes, int n_in,
                              void* d_out, int out_size, void* d_ws, size_t ws_size,
                              hipStream_t stream) {
    const float* x      = (const float*)d_in[0];   // [4,2048,2048]
    const float* qkv    = (const float*)d_in[1];   // [2048,6144]
    const float* o_proj = (const float*)d_in[2];   // [2048,2048]
    const float* gamma  = (const float*)d_in[3];
    const float* beta   = (const float*)d_in[4];
    float* out = (float*)d_out;                    // [8192,2048]

    char* w = (char*)d_ws;
    unsigned short* xn      = (unsigned short*)(w);              // 33,554,432 B [8192,2048]; later aliased as scores
    unsigned short* w_t     = (unsigned short*)(w + 33554432);   // 25,165,824 B [6144,2048] qkv^T
    unsigned short* o_t     = (unsigned short*)(w + 58720256);   //  8,388,608 B [2048,2048] o_proj^T
    unsigned short* qkv_out = (unsigned short*)(w + 67108864);   // 100,663,296 B [8192,6144] q|k|v (q slot reused for attn_out)
    unsigned short* v_t     = (unsigned short*)(w + 167772160);  // 33,554,432 B [4][2048,2048] v^T
    unsigned short* scores  = xn;                                // alias: x_norm dead after GEMM1

    // 1) LayerNorm + cast
    ln_kernel<<<NROWS, 256, 0, stream>>>(x, gamma, beta, xn);
    // 2) weight transposes + cast
    transp_f32_bf16<<<dim3(192, 64), 256, 0, stream>>>(qkv, N3, w_t, HD);
    transp_f32_bf16<<<dim3(64, 64), 256, 0, stream>>>(o_proj, HD, o_t, HD);
    // 3) QKV projection: [8192,2048] @ [2048,6144] -> bf16 [8192,6144]
    gemm_nt<0><<<dim3(48, 64, 1), 256, 0, stream>>>(xn, HD, 0L, w_t, HD, 0L,
        (void*)qkv_out, N3, 0L, HD, 0, 1.0f, nullptr);
    // 4) v^T per batch: [s,dk] -> [dk,s]
    transp_bf16<<<dim3(64, 64, 4), 256, 0, stream>>>(qkv_out + 4096, N3, (long)S_LEN * N3,
        v_t, S_LEN, (long)HD * S_LEN);
    // 5) scores = q @ k^T * scale (skip upper-triangle blocks)
    float scale = 0.022097086912079608f; // 1/sqrt(2048)
    gemm_nt<1><<<dim3(16, 16, 4), 256, 0, stream>>>(qkv_out, N3, (long)S_LEN * N3,
        qkv_out + 2048, N3, (long)S_LEN * N3,
        (void*)scores, S_LEN, (long)S_LEN * S_LEN, HD, 1, scale, nullptr);
    // 6) causal softmax in place (zeroes t>s so PV GEMM reads clean zeros)
    softmax_causal<<<NROWS, 256, 0, stream>>>(scores);
    // 7) attn_out = P @ V  (K clipped at diagonal block), into q slot of qkv_out
    gemm_nt<0><<<dim3(16, 16, 4), 256, 0, stream>>>(scores, S_LEN, (long)S_LEN * S_LEN,
        v_t, S_LEN, (long)HD * S_LEN,
        (void*)qkv_out, N3, (long)S_LEN * N3, S_LEN, 2, 1.0f, nullptr);
    // 8) out = attn_out @ o_proj + x (fp32)
    gemm_nt<2><<<dim3(16, 64, 1), 256, 0, stream>>>(qkv_out, N3, 0L, o_t, HD, 0L,
        (void*)out, HD, 0L, HD, 0, 1.0f, x);
}

// Round 2
// 660.411 us; speedup vs baseline: 1.1422x; 1.1422x over previous
//
#include <hip/hip_runtime.h>
#include <stdint.h>

typedef short short8 __attribute__((ext_vector_type(8)));
typedef unsigned short ushort8 __attribute__((ext_vector_type(8)));
typedef unsigned short ushort4v __attribute__((ext_vector_type(4)));
typedef float f32x4 __attribute__((ext_vector_type(4)));

#define HD 2048
#define S_LEN 2048
#define NROWS 8192
#define N3 6144

typedef __attribute__((address_space(3))) void lds_void_t;
typedef __attribute__((address_space(1))) void g_void_t;

__device__ inline void gload_lds16(const void* g, void* l) {
    __builtin_amdgcn_global_load_lds((g_void_t*)g, (lds_void_t*)l, 16, 0, 0);
}

__device__ inline unsigned short f2bf(float f) {
    unsigned u = __float_as_uint(f);
    unsigned r = (u + 0x7FFFu + ((u >> 16) & 1u)) >> 16;
    return (unsigned short)r;
}
__device__ inline float bf2f(unsigned short h) {
    return __uint_as_float(((unsigned)h) << 16);
}

// ---------------- LayerNorm fp32 -> bf16 ----------------
__global__ __launch_bounds__(256) void ln_kernel(const float* __restrict__ x,
    const float* __restrict__ gamma, const float* __restrict__ beta,
    unsigned short* __restrict__ xn) {
    int row = blockIdx.x;
    const float* xr = x + (size_t)row * HD;
    int tid = threadIdx.x;
    float v[8];
    float4 a = *(const float4*)(xr + tid * 8);
    float4 b = *(const float4*)(xr + tid * 8 + 4);
    v[0]=a.x; v[1]=a.y; v[2]=a.z; v[3]=a.w; v[4]=b.x; v[5]=b.y; v[6]=b.z; v[7]=b.w;
    float s = 0.f, ss = 0.f;
#pragma unroll
    for (int e = 0; e < 8; e++) { s += v[e]; ss += v[e] * v[e]; }
    for (int off = 32; off > 0; off >>= 1) {
        s += __shfl_down(s, off);
        ss += __shfl_down(ss, off);
    }
    __shared__ float red[10];
    int wave = tid >> 6, lane = tid & 63;
    if (lane == 0) { red[wave] = s; red[4 + wave] = ss; }
    __syncthreads();
    if (tid == 0) {
        float S = red[0] + red[1] + red[2] + red[3];
        float SS = red[4] + red[5] + red[6] + red[7];
        float mu = S * (1.0f / HD);
        float var = SS * (1.0f / HD) - mu * mu;
        red[8] = mu;
        red[9] = rsqrtf(var + 1e-5f);
    }
    __syncthreads();
    float mu = red[8], rstd = red[9];
#pragma unroll
    for (int e = 0; e < 8; e++) {
        int c = tid * 8 + e;
        float val = (v[e] - mu) * rstd * gamma[c] + beta[c];
        xn[(size_t)row * HD + c] = f2bf(val);
    }
}

// ---------------- transpose + cast fp32 -> bf16 ----------------
__global__ __launch_bounds__(256) void transp_f32_bf16(const float* __restrict__ src, int ld_s,
    unsigned short* __restrict__ dst, int ld_d) {
    __shared__ float tile[32][33];
    int c0 = blockIdx.x * 32, r0 = blockIdx.y * 32;
    int tc = threadIdx.x & 31, tr = threadIdx.x >> 5; // tr 0..7
#pragma unroll
    for (int i = 0; i < 32; i += 8)
        tile[tr + i][tc] = src[(size_t)(r0 + tr + i) * ld_s + c0 + tc];
    __syncthreads();
#pragma unroll
    for (int i = 0; i < 32; i += 8)
        dst[(size_t)(c0 + tr + i) * ld_d + r0 + tc] = f2bf(tile[tc][tr + i]);
}

// ---------------- causal softmax over bf16 scores, in place ----------------
__global__ __launch_bounds__(256) void softmax_causal(unsigned short* __restrict__ sc) {
    int r = blockIdx.x;            // 0..8191 = b*2048+s
    int s = r & (S_LEN - 1);
    unsigned short* row = sc + (size_t)r * S_LEN;
    int tid = threadIdx.x;
    ushort8 u = *(const ushort8*)(row + tid * 8);
    float v[8];
    float mx = -3.0e38f;
#pragma unroll
    for (int e = 0; e < 8; e++) {
        int t = tid * 8 + e;
        float f = bf2f(u[e]);
        v[e] = (t <= s) ? f : -3.0e38f;
        mx = fmaxf(mx, v[e]);
    }
    for (int off = 32; off > 0; off >>= 1) mx = fmaxf(mx, __shfl_down(mx, off));
    __shared__ float red[8];
    int wave = tid >> 6, lane = tid & 63;
    if (lane == 0) red[wave] = mx;
    __syncthreads();
    mx = fmaxf(fmaxf(red[0], red[1]), fmaxf(red[2], red[3]));
    float ex[8];
    float sum = 0.f;
#pragma unroll
    for (int e = 0; e < 8; e++) {
        ex[e] = (v[e] > -1.0e38f) ? __expf(v[e] - mx) : 0.f;
        sum += ex[e];
    }
    for (int off = 32; off > 0; off >>= 1) sum += __shfl_down(sum, off);
    if (lane == 0) red[4 + wave] = sum;
    __syncthreads();
    float inv = 1.0f / (red[4] + red[5] + red[6] + red[7]);
#pragma unroll
    for (int e = 0; e < 8; e++) {
        row[tid * 8 + e] = f2bf(ex[e] * inv);
    }
}

// ---------------- NT GEMM: C[m,n] = sum_k A[m,k] * Bt[n,k] ----------------
// 128x128 tile, BK=64 (two k-half panels in LDS), 4 waves (2x2), each wave
// 64x64 = 4x4 of 16x16x32 MFMA, two k-steps per staged tile.
// EPI 0: bf16 store. EPI 1: bf16 store * scale. EPI 2: fp32 store + residual.
// EPI 3: bf16 store for n<4096 (q,k), packed-transposed store into vt for n>=4096 (v).
// causal 0: none. 1: skip blocks with bx>by (scores). 2: clip K at (by+1)*128 (PV).
// causal!=0 remaps by longest-first.
template <int EPI>
__global__ __launch_bounds__(256) void gemm_nt(
    const unsigned short* __restrict__ Ab, int lda, long sAz,
    const unsigned short* __restrict__ Bb, int ldb, long sBz,
    void* __restrict__ Cb, int ldc, long sCz,
    int kdim, int causal, float scale, const float* __restrict__ resid,
    unsigned short* __restrict__ vt) {
    int bx = blockIdx.x, by = blockIdx.y, bz = blockIdx.z;
    if (causal) by = gridDim.y - 1 - by;   // longest-first dispatch
    if (causal == 1 && bx > by) return;
    const unsigned short* A = Ab + (size_t)bz * sAz;
    const unsigned short* Bt = Bb + (size_t)bz * sBz;
    int kmax = kdim;
    if (causal == 2) { int km = (by + 1) * 128; if (km < kmax) kmax = km; }
    int m0 = by * 128, n0 = bx * 128;

    // two k-half panels: element (row r, k kk) at [ (kk>>5)*4096 + r*32 + (kk&31) ]
    __shared__ unsigned short lA[128 * 64];
    __shared__ unsigned short lB[128 * 64];

    int tid = threadIdx.x;
    int wave = tid >> 6, lane = tid & 63;
    int quad = lane >> 4, l16 = lane & 15;
    int wr = wave >> 1, wc = wave & 1;

    // staging: wave w covers rows w*32..w*32+31; instr (r16, h):
    //  lane -> row w*32 + r16*16 + (lane>>2), k = h*32 + (lane&3)*8
    int rstage = wave * 32 + (lane >> 2);
    int ck = (lane & 3) * 8;
    const unsigned short* gA[2][2];
    const unsigned short* gB[2][2];
    unsigned short* ldA[2][2];
    unsigned short* ldB[2][2];
#pragma unroll
    for (int r16 = 0; r16 < 2; r16++)
#pragma unroll
        for (int h = 0; h < 2; h++) {
            gA[r16][h] = A + (size_t)(m0 + rstage + r16 * 16) * lda + h * 32 + ck;
            gB[r16][h] = Bt + (size_t)(n0 + rstage + r16 * 16) * ldb + h * 32 + ck;
            ldA[r16][h] = &lA[h * 4096 + (wave * 32 + r16 * 16) * 32];
            ldB[r16][h] = &lB[h * 4096 + (wave * 32 + r16 * 16) * 32];
        }

    f32x4 acc[4][4] = {};

    for (int k0 = 0; k0 < kmax; k0 += 64) {
        __syncthreads();
#pragma unroll
        for (int r16 = 0; r16 < 2; r16++)
#pragma unroll
            for (int h = 0; h < 2; h++) {
                gload_lds16(gA[r16][h], ldA[r16][h]);
                gload_lds16(gB[r16][h], ldB[r16][h]);
            }
        __syncthreads();
#pragma unroll
        for (int h = 0; h < 2; h++) {
            short8 af[4], bfr[4];
#pragma unroll
            for (int i = 0; i < 4; i++)
                af[i] = *(const short8*)&lA[h * 4096 + (wr * 64 + i * 16 + l16) * 32 + quad * 8];
#pragma unroll
            for (int j = 0; j < 4; j++)
                bfr[j] = *(const short8*)&lB[h * 4096 + (wc * 64 + j * 16 + l16) * 32 + quad * 8];
#pragma unroll
            for (int i = 0; i < 4; i++)
#pragma unroll
                for (int j = 0; j < 4; j++)
                    acc[i][j] = __builtin_amdgcn_mfma_f32_16x16x32_bf16(af[i], bfr[j], acc[i][j], 0, 0, 0);
        }
#pragma unroll
        for (int r16 = 0; r16 < 2; r16++)
#pragma unroll
            for (int h = 0; h < 2; h++) { gA[r16][h] += 64; gB[r16][h] += 64; }
    }

    // epilogue: C[row = m0+wr*64+i*16+quad*4+r][col = n0+wc*64+j*16+l16]
    int row0 = m0 + wr * 64 + quad * 4;
    int col0 = n0 + wc * 64 + l16;
    if (EPI == 3 && n0 >= 4096) {
        // v columns: write transposed into vt[batch][kcol][s], packed 4 s-values
        int batch = m0 >> 11;
        int sl0 = (m0 & 2047) + wr * 64 + quad * 4;
#pragma unroll
        for (int j = 0; j < 4; j++) {
            int kcol = (n0 - 4096) + wc * 64 + j * 16 + l16;
            unsigned short* base = vt + (size_t)batch * S_LEN * S_LEN + (size_t)kcol * S_LEN + sl0;
#pragma unroll
            for (int i = 0; i < 4; i++) {
                ushort4v p;
#pragma unroll
                for (int r = 0; r < 4; r++) p[r] = f2bf(acc[i][j][r]);
                *(ushort4v*)(base + i * 16) = p;
            }
        }
    } else if (EPI == 0 || EPI == 1 || EPI == 3) {
        unsigned short* C = (unsigned short*)Cb + (size_t)bz * sCz;
#pragma unroll
        for (int i = 0; i < 4; i++)
#pragma unroll
            for (int r = 0; r < 4; r++) {
                int row = row0 + i * 16 + r;
#pragma unroll
                for (int j = 0; j < 4; j++) {
                    float v = acc[i][j][r];
                    if (EPI == 1) v *= scale;
                    C[(size_t)row * ldc + col0 + j * 16] = f2bf(v);
                }
            }
    } else {
        float* C = (float*)Cb + (size_t)bz * sCz;
#pragma unroll
        for (int i = 0; i < 4; i++)
#pragma unroll
            for (int r = 0; r < 4; r++) {
                int row = row0 + i * 16 + r;
#pragma unroll
                for (int j = 0; j < 4; j++) {
                    int col = col0 + j * 16;
                    C[(size_t)row * ldc + col] = acc[i][j][r] + resid[(size_t)row * ldc + col];
                }
            }
    }
}

extern "C" void kernel_launch(void* const* d_in, const int* in_sizes, int n_in,
                              void* d_out, int out_size, void* d_ws, size_t ws_size,
                              hipStream_t stream) {
    const float* x      = (const float*)d_in[0];   // [4,2048,2048]
    const float* qkv    = (const float*)d_in[1];   // [2048,6144]
    const float* o_proj = (const float*)d_in[2];   // [2048,2048]
    const float* gamma  = (const float*)d_in[3];
    const float* beta   = (const float*)d_in[4];
    float* out = (float*)d_out;                    // [8192,2048]

    char* w = (char*)d_ws;
    unsigned short* xn      = (unsigned short*)(w);              // 33,554,432 B [8192,2048]; later aliased as scores
    unsigned short* w_t     = (unsigned short*)(w + 33554432);   // 25,165,824 B [6144,2048] qkv^T
    unsigned short* o_t     = (unsigned short*)(w + 58720256);   //  8,388,608 B [2048,2048] o_proj^T
    unsigned short* qkv_out = (unsigned short*)(w + 67108864);   // 100,663,296 B [8192,6144] q|k (v slot unused; q slot reused for attn_out)
    unsigned short* v_t     = (unsigned short*)(w + 167772160);  // 33,554,432 B [4][2048,2048] v^T (written directly by GEMM1)
    unsigned short* scores  = xn;                                // alias: x_norm dead after GEMM1

    // 1) LayerNorm + cast
    ln_kernel<<<NROWS, 256, 0, stream>>>(x, gamma, beta, xn);
    // 2) weight transposes + cast
    transp_f32_bf16<<<dim3(192, 64), 256, 0, stream>>>(qkv, N3, w_t, HD);
    transp_f32_bf16<<<dim3(64, 64), 256, 0, stream>>>(o_proj, HD, o_t, HD);
    // 3) QKV projection: [8192,2048] @ [2048,6144]; q,k row-major bf16, v written transposed to v_t
    gemm_nt<3><<<dim3(48, 64, 1), 256, 0, stream>>>(xn, HD, 0L, w_t, HD, 0L,
        (void*)qkv_out, N3, 0L, HD, 0, 1.0f, nullptr, v_t);
    // 4) scores = q @ k^T * scale (skip upper-triangle blocks, longest rows first)
    float scale = 0.022097086912079608f; // 1/sqrt(2048)
    gemm_nt<1><<<dim3(16, 16, 4), 256, 0, stream>>>(qkv_out, N3, (long)S_LEN * N3,
        qkv_out + 2048, N3, (long)S_LEN * N3,
        (void*)scores, S_LEN, (long)S_LEN * S_LEN, HD, 1, scale, nullptr, nullptr);
    // 5) causal softmax in place (zeroes t>s so PV GEMM reads clean zeros)
    softmax_causal<<<NROWS, 256, 0, stream>>>(scores);
    // 6) attn_out = P @ V  (K clipped at diagonal block, longest-first), into q slot of qkv_out
    gemm_nt<0><<<dim3(16, 16, 4), 256, 0, stream>>>(scores, S_LEN, (long)S_LEN * S_LEN,
        v_t, S_LEN, (long)HD * S_LEN,
        (void*)qkv_out, N3, (long)S_LEN * N3, S_LEN, 2, 1.0f, nullptr, nullptr);
    // 7) out = attn_out @ o_proj + x (fp32)
    gemm_nt<2><<<dim3(16, 64, 1), 256, 0, stream>>>(qkv_out, N3, 0L, o_t, HD, 0L,
        (void*)out, HD, 0L, HD, 0, 1.0f, x, nullptr);
}